// Round 5
// baseline (473.549 us; speedup 1.0000x reference)
//
#include <hip/hip_runtime.h>
#include <math.h>

#define N_NODES 8192
#define N_COMM 16
#define DIMS 64
#define ROWS 32                      // ricci rows per block (i-chunk)
#define JS 1024                      // j-strip per block: 256 thr x 4
#define NJB (N_NODES / JS)           // 8 j-strips
#define NIB (N_NODES / ROWS)         // 256 i-chunks -> grid 2048
#define PITS (N_NODES + 64)          // piT row stride (padded: L2 channel spread)

typedef float v4f __attribute__((ext_vector_type(4)));

// ---------------------------------------------------------------------------
// Kernel 1: pi[i,k] = softmax_k( sqrt(d_euc^2 + d_lor^2 + d_sph^2) )
// One lane per (node, k): t = i*16 + k. 16-lane softmax via shfl_xor(1,2,4,8).
// Writes pi row-major AND transposed padded piT. Thread 0 zeroes accum+ctr.
// ---------------------------------------------------------------------------
__global__ __launch_bounds__(256) void k_pi(
    const float* __restrict__ node,   // (3, 8192, 64)
    const float* __restrict__ comm,   // (16, 64)
    float* __restrict__ pi,           // (8192, 16)
    float* __restrict__ piT,          // (16, PITS)
    double* __restrict__ accum,       // [0]=intra, [1]=inter
    unsigned* __restrict__ ctr)       // k_main finish counter
{
  const int t = blockIdx.x * blockDim.x + threadIdx.x;  // 0..131071
  if (t == 0) { accum[0] = 0.0; accum[1] = 0.0; *ctr = 0u; }
  const int i = t >> 4;
  const int k = t & 15;

  const float* xe = node + (size_t)i * DIMS;                  // Euclidean (curv 0)
  const float* xl = xe + (size_t)N_NODES * DIMS;              // Lorentz  (curv -1)
  const float* xs = xl + (size_t)N_NODES * DIMS;              // Sphere   (curv +1)
  const float* c  = comm + k * DIMS;

  float de = 0.f, il = 0.f, isp = 0.f;
#pragma unroll
  for (int d = 0; d < DIMS; d += 4) {
    v4f a  = *(const v4f*)(xe + d);
    v4f b  = *(const v4f*)(xl + d);
    v4f e  = *(const v4f*)(xs + d);
    v4f cv = *(const v4f*)(c + d);
    v4f df = a - cv;
    de  += df.x * df.x + df.y * df.y + df.z * df.z + df.w * df.w;
    il  += b.x * cv.x + b.y * cv.y + b.z * cv.z + b.w * cv.w;
    isp += e.x * cv.x + e.y * cv.y + e.z * cv.z + e.w * cv.w;
  }

  // Lorentz (kk = 1): lip = <x,c> - 2*x0*c0 ; d = arccosh(max(-lip, 1+eps))
  float lip = il - 2.0f * xl[0] * c[0];
  float arg = fmaxf(-lip, 1.0f + 1e-7f);
  float d1  = acoshf(arg);
  // Sphere: d = arccos(clip(<x,c>, -1+eps, 1-eps))
  float cs = fminf(fmaxf(isp, -1.0f + 1e-7f), 1.0f - 1e-7f);
  float d2 = acosf(cs);

  float dn = sqrtf(de + d1 * d1 + d2 * d2);

  // softmax over the 16 lanes sharing this node (lane mask bits 0..3)
  float m = dn;
#pragma unroll
  for (int off = 1; off < 16; off <<= 1) m = fmaxf(m, __shfl_xor(m, off));
  float ex = expf(dn - m);
  float ss = ex;
#pragma unroll
  for (int off = 1; off < 16; off <<= 1) ss += __shfl_xor(ss, off);

  float v = ex / ss;
  pi[t] = v;                     // coalesced
  piT[k * PITS + i] = v;         // scattered, tiny (one store/thread)
}

// ---------------------------------------------------------------------------
// Kernel 2: 2-D tiling, block = (32 rows) x (1024-j strip), thread = j-quad.
// R3 POST-MORTEM: VGPR_Count was 64 while p[16] v4f alone needs 64 -> the
// compiler spilled/rematerialized the pi fragments INSIDE the loop; every
// row paid latency-exposed scratch/piT reloads (the real ~4800 cyc/row).
// Fixes:
//   (a) __launch_bounds__(256, 1): min 1 wave/EU -> allocator freed to use
//       the ~130 VGPRs this dataflow needs (R0 was faster than R2/R3 purely
//       because it got ~190 VGPRs and spilled nothing).
//   (b) ALL hot state in NAMED registers (p0..p15, a0..a3/b0..b3 double
//       buffer) -- no arrays, no scratch-demotion risk.
//   (c) 8 groups x 4 rows: group prefetches next group's 4 ricci quads
//       FIRST (counted vmcnt, 4-8 row distance), then 4x(broadcast
//       ds_read_b128 pi row + 80 FMA). vmcnt stream stays pure ricci.
// Epilogue: last block finalizes (fused k_final).
// (R4 bench was an infra failure -- this is a resubmission of the same
//  structure so the VGPR/spill prediction can be tested.)
// ---------------------------------------------------------------------------
__global__ __launch_bounds__(256, 1) void k_main(
    const float* __restrict__ ricci,   // (8192, 8192)
    const float* __restrict__ pi,      // (8192, 16) row-major
    const float* __restrict__ piT,     // (16, PITS)
    const float* __restrict__ alpha,   // scalar
    double* __restrict__ accum,        // [0]=intra_sum, [1]=inter_sum
    unsigned* __restrict__ ctr,
    float* __restrict__ out)
{
  const int tid = threadIdx.x;
  const int jb  = blockIdx.x & (NJB - 1);   // j-strip
  const int ib  = blockIdx.x >> 3;          // i-chunk (log2(NJB)=3)
  const int i0  = ib * ROWS;
  const int j   = jb * JS + tid * 4;

  // stage pi rows i0..i0+31 into LDS (512 floats, 2 coalesced loads)
  __shared__ float prs[ROWS * N_COMM];
  {
    const float* src = pi + (size_t)i0 * N_COMM;
    prs[tid]       = src[tid];
    prs[tid + 256] = src[tid + 256];
  }

  // one-time pi column fragments for this thread's j-quad -> NAMED registers
  const float* pT = piT + j;
#define LOADP(n) v4f p##n = *(const v4f*)(pT + (size_t)(n) * PITS)
  LOADP(0);  LOADP(1);  LOADP(2);  LOADP(3);
  LOADP(4);  LOADP(5);  LOADP(6);  LOADP(7);
  LOADP(8);  LOADP(9);  LOADP(10); LOADP(11);
  LOADP(12); LOADP(13); LOADP(14); LOADP(15);
#undef LOADP

  __syncthreads();

  const float* rptr = ricci + (size_t)i0 * N_NODES + j;

  float fi0 = 0.f, fi1 = 0.f, fi2 = 0.f, fi3 = 0.f, finter = 0.f;

  // double-buffered row quads (named registers)
  v4f a0 = *(const v4f*)(rptr + (size_t)0 * N_NODES);
  v4f a1 = *(const v4f*)(rptr + (size_t)1 * N_NODES);
  v4f a2 = *(const v4f*)(rptr + (size_t)2 * N_NODES);
  v4f a3 = *(const v4f*)(rptr + (size_t)3 * N_NODES);
  v4f b0 = {}, b1 = {}, b2 = {}, b3 = {};

#define ROWFMA(rr, row)                                                     \
  {                                                                         \
    const v4f* pr = (const v4f*)&prs[(row) * N_COMM];                       \
    v4f pa = pr[0], pb = pr[1], pc = pr[2], pd = pr[3];                     \
    float s;                                                                \
    s = rr.x*p0.x  + rr.y*p0.y  + rr.z*p0.z  + rr.w*p0.w;  fi0 += pa.x*s;   \
    s = rr.x*p1.x  + rr.y*p1.y  + rr.z*p1.z  + rr.w*p1.w;  fi1 += pa.y*s;   \
    s = rr.x*p2.x  + rr.y*p2.y  + rr.z*p2.z  + rr.w*p2.w;  fi2 += pa.z*s;   \
    s = rr.x*p3.x  + rr.y*p3.y  + rr.z*p3.z  + rr.w*p3.w;  fi3 += pa.w*s;   \
    s = rr.x*p4.x  + rr.y*p4.y  + rr.z*p4.z  + rr.w*p4.w;  fi0 += pb.x*s;   \
    s = rr.x*p5.x  + rr.y*p5.y  + rr.z*p5.z  + rr.w*p5.w;  fi1 += pb.y*s;   \
    s = rr.x*p6.x  + rr.y*p6.y  + rr.z*p6.z  + rr.w*p6.w;  fi2 += pb.z*s;   \
    s = rr.x*p7.x  + rr.y*p7.y  + rr.z*p7.z  + rr.w*p7.w;  fi3 += pb.w*s;   \
    s = rr.x*p8.x  + rr.y*p8.y  + rr.z*p8.z  + rr.w*p8.w;  fi0 += pc.x*s;   \
    s = rr.x*p9.x  + rr.y*p9.y  + rr.z*p9.z  + rr.w*p9.w;  fi1 += pc.y*s;   \
    s = rr.x*p10.x + rr.y*p10.y + rr.z*p10.z + rr.w*p10.w; fi2 += pc.z*s;   \
    s = rr.x*p11.x + rr.y*p11.y + rr.z*p11.z + rr.w*p11.w; fi3 += pc.w*s;   \
    s = rr.x*p12.x + rr.y*p12.y + rr.z*p12.z + rr.w*p12.w; fi0 += pd.x*s;   \
    s = rr.x*p13.x + rr.y*p13.y + rr.z*p13.z + rr.w*p13.w; fi1 += pd.y*s;   \
    s = rr.x*p14.x + rr.y*p14.y + rr.z*p14.z + rr.w*p14.w; fi2 += pd.z*s;   \
    s = rr.x*p15.x + rr.y*p15.y + rr.z*p15.z + rr.w*p15.w; fi3 += pd.w*s;   \
    finter += (rr.x + rr.y) + (rr.z + rr.w);                                \
  }

  // group g: prefetch rows 4(g+1)..4(g+1)+3 into NXT, compute CUR rows 4g..
#define GROUP(g, C0, C1, C2, C3, N0, N1, N2, N3)                            \
  {                                                                         \
    if ((g) + 1 < ROWS / 4) {                                               \
      N0 = *(const v4f*)(rptr + (size_t)((g) * 4 + 4) * N_NODES);           \
      N1 = *(const v4f*)(rptr + (size_t)((g) * 4 + 5) * N_NODES);           \
      N2 = *(const v4f*)(rptr + (size_t)((g) * 4 + 6) * N_NODES);           \
      N3 = *(const v4f*)(rptr + (size_t)((g) * 4 + 7) * N_NODES);           \
    }                                                                       \
    ROWFMA(C0, (g) * 4 + 0)                                                 \
    ROWFMA(C1, (g) * 4 + 1)                                                 \
    ROWFMA(C2, (g) * 4 + 2)                                                 \
    ROWFMA(C3, (g) * 4 + 3)                                                 \
  }

  GROUP(0, a0, a1, a2, a3, b0, b1, b2, b3)
  GROUP(1, b0, b1, b2, b3, a0, a1, a2, a3)
  GROUP(2, a0, a1, a2, a3, b0, b1, b2, b3)
  GROUP(3, b0, b1, b2, b3, a0, a1, a2, a3)
  GROUP(4, a0, a1, a2, a3, b0, b1, b2, b3)
  GROUP(5, b0, b1, b2, b3, a0, a1, a2, a3)
  GROUP(6, a0, a1, a2, a3, b0, b1, b2, b3)
  GROUP(7, b0, b1, b2, b3, a0, a1, a2, a3)

#undef GROUP
#undef ROWFMA

  float fintra = (fi0 + fi1) + (fi2 + fi3);

  // wave reduce (64 lanes) in double, then block reduce, 2 atomics/block
  double di = (double)fintra, dn = (double)finter;
#pragma unroll
  for (int off = 32; off > 0; off >>= 1) {
    di += __shfl_down(di, off);
    dn += __shfl_down(dn, off);
  }
  __shared__ double red[8];
  const int w = tid >> 6;
  if ((tid & 63) == 0) { red[w] = di; red[4 + w] = dn; }
  __syncthreads();
  if (tid == 0) {
    atomicAdd(&accum[0], red[0] + red[1] + red[2] + red[3]);
    atomicAdd(&accum[1], red[4] + red[5] + red[6] + red[7]);
    // last-block finalize (fused k_final): device-scope atomics + fences
    __threadfence();
    unsigned prev = atomicAdd(ctr, 1u);
    if (prev == (unsigned)gridDim.x - 1u) {
      __threadfence();
      double ia  = atomicAdd(&accum[0], 0.0);   // coherent device-scope read
      double ir2 = atomicAdd(&accum[1], 0.0);
      const double KN  = (double)N_COMM * (double)N_NODES;
      const double KKN = (double)N_COMM * (double)N_COMM * (double)N_NODES;
      out[0] = (float)((double)alpha[0] * (ia / KN) - ir2 / KKN);
    }
  }
}

extern "C" void kernel_launch(void* const* d_in, const int* in_sizes, int n_in,
                              void* d_out, int out_size, void* d_ws, size_t ws_size,
                              hipStream_t stream) {
  (void)in_sizes; (void)n_in; (void)out_size; (void)ws_size;

  const float* node  = (const float*)d_in[0];  // (3, 8192, 64) fp32
  const float* comm  = (const float*)d_in[1];  // (16, 64) fp32
  const float* ricci = (const float*)d_in[2];  // (8192, 8192) fp32
  const float* alpha = (const float*)d_in[3];  // scalar fp32
  float* out = (float*)d_out;

  double*   accum = (double*)d_ws;                         // 2 doubles @ 0
  unsigned* ctr   = (unsigned*)((char*)d_ws + 16);         // finish counter
  float*    pi    = (float*)((char*)d_ws + 64);            // 512 KB
  float*    piT   = (float*)((char*)d_ws + 64 + 524288);   // 16*PITS*4 = 528 KB

  // accum/ctr zeroed by k_pi thread 0 (in-stream, before k_main) -- no memset.
  hipLaunchKernelGGL(k_pi,   dim3((N_NODES * N_COMM) / 256), dim3(256), 0, stream,
                     node, comm, pi, piT, accum, ctr);
  hipLaunchKernelGGL(k_main, dim3(NIB * NJB), dim3(256), 0, stream,
                     ricci, pi, piT, alpha, accum, ctr, out);
}